// Round 17
// baseline (1992.929 us; speedup 1.0000x reference)
//
#include <hip/hip_runtime.h>

#define D       256
#define DH      32
#define FFDIM   1024
#define VOCAB   2048
#define GENLEN  16
#define BATCH   8
#define NSLOT   7
#define TF      17
#define NLAYER  4
#define NSL     16

#define SCOPE_AGENT __HIP_MEMORY_SCOPE_AGENT

typedef float    f32x4 __attribute__((ext_vector_type(4)));
typedef unsigned u32x4 __attribute__((ext_vector_type(4)));
typedef unsigned long long u64;

struct Params {
  const float *slots, *W_slot_proj, *dict_emb, *pe;
  const float *ln_self_w, *ln_self_b, *Wq_s, *Wk_s, *Wv_s, *Wo_s;
  const float *ln_cross_w, *ln_cross_b, *Wq_c, *Wk_c, *Wv_c, *Wo_c;
  const float *ln_ffn_w, *ln_ffn_b, *W1, *b1, *W2, *b2;
  const float *ln_f_w, *ln_f_b, *W_out;
  float *enc;
  u64 *P0, *P1, *tri;
  unsigned *flags;
  float *out_z, *out_lp;
};

__device__ __forceinline__ float cload(const float* p) {
  return __hip_atomic_load(p, __ATOMIC_RELAXED, SCOPE_AGENT);
}
__device__ __forceinline__ void cstore(float* p, float v) {
  __hip_atomic_store(p, v, __ATOMIC_RELAXED, SCOPE_AGENT);
}
__device__ __forceinline__ u64 cload64(const u64* p) {
  return __hip_atomic_load(p, __ATOMIC_RELAXED, SCOPE_AGENT);
}
__device__ __forceinline__ void cstore64(u64* p, u64 v) {
  __hip_atomic_store(p, v, __ATOMIC_RELAXED, SCOPE_AGENT);
}
__device__ __forceinline__ u64 packt(unsigned tag, float v) {
  return ((u64)tag << 32) | (u64)__float_as_uint(v);
}

__device__ __forceinline__ float blockSum(float v, float* red) {
  #pragma unroll
  for (int o = 32; o > 0; o >>= 1) v += __shfl_down(v, o);
  const int lane = threadIdx.x & 63, w = threadIdx.x >> 6;
  if (lane == 0) red[w] = v;
  __syncthreads();
  float s = red[0] + red[1] + red[2] + red[3];
  __syncthreads();
  return s;
}

// ---- streaming GEMV, BOTH initial 32-blocks preloaded (issued post-fold,
// overlapping LN) -> first exposed stall removed. FP order == dotStreamPre. ----
template<int N>
__device__ __forceinline__ float dotStreamPre2(const float* __restrict__ W,
                                               const float* __restrict__ h,
                                               int i0, int ld,
                                               const float* __restrict__ preA,
                                               const float* __restrict__ preB) {
  float pA[32], pB[32];
  #pragma unroll
  for (int k = 0; k < 32; ++k) pA[k] = preA[k];
  #pragma unroll
  for (int k = 0; k < 32; ++k) pB[k] = preB[k];
  float acc = 0.f;
  #pragma unroll 1
  for (int u = 0; u < N; u += 64) {
    const f32x4* h4 = reinterpret_cast<const f32x4*>(h + i0 + u);
    #pragma unroll
    for (int k = 0; k < 8; ++k) {
      const f32x4 hv = h4[k];
      acc = fmaf(hv.x, pA[4*k+0], acc); acc = fmaf(hv.y, pA[4*k+1], acc);
      acc = fmaf(hv.z, pA[4*k+2], acc); acc = fmaf(hv.w, pA[4*k+3], acc);
    }
    if (u + 64 < N) {
      #pragma unroll
      for (int k = 0; k < 32; ++k) pA[k] = W[(size_t)(i0 + u + 64 + k) * ld];
    }
    #pragma unroll
    for (int k = 0; k < 8; ++k) {
      const f32x4 hv = h4[8 + k];
      acc = fmaf(hv.x, pB[4*k+0], acc); acc = fmaf(hv.y, pB[4*k+1], acc);
      acc = fmaf(hv.z, pB[4*k+2], acc); acc = fmaf(hv.w, pB[4*k+3], acc);
    }
    if (u + 96 < N) {
      #pragma unroll
      for (int k = 0; k < 32; ++k) pB[k] = W[(size_t)(i0 + u + 96 + k) * ld];
    }
  }
  return acc;
}

// 64-row dot with BOTH halves preloaded (zero runtime weight loads)
__device__ __forceinline__ float dot64_2(const float* __restrict__ h, int i0,
                                         const float* __restrict__ A,
                                         const float* __restrict__ B) {
  float acc = 0.f;
  const f32x4* h4 = reinterpret_cast<const f32x4*>(h + i0);
  #pragma unroll
  for (int k = 0; k < 8; ++k) {
    const f32x4 hv = h4[k];
    acc = fmaf(hv.x, A[4*k+0], acc); acc = fmaf(hv.y, A[4*k+1], acc);
    acc = fmaf(hv.z, A[4*k+2], acc); acc = fmaf(hv.w, A[4*k+3], acc);
  }
  #pragma unroll
  for (int k = 0; k < 8; ++k) {
    const f32x4 hv = h4[8 + k];
    acc = fmaf(hv.x, B[4*k+0], acc); acc = fmaf(hv.y, B[4*k+1], acc);
    acc = fmaf(hv.z, B[4*k+2], acc); acc = fmaf(hv.w, B[4*k+3], acc);
  }
  return acc;
}

__device__ __forceinline__ float dot32(const float* __restrict__ w,
                                       const float* __restrict__ h, int i0) {
  float acc = 0.f;
  const f32x4* h4 = reinterpret_cast<const f32x4*>(h + i0);
  #pragma unroll
  for (int k = 0; k < 8; ++k) {
    const f32x4 hv = h4[k];
    acc = fmaf(hv.x, w[4*k+0], acc); acc = fmaf(hv.y, w[4*k+1], acc);
    acc = fmaf(hv.z, w[4*k+2], acc); acc = fmaf(hv.w, w[4*k+3], acc);
  }
  return acc;
}

__global__ __launch_bounds__(256, 1) void mega_kernel(Params p)
{
  const int blk = blockIdx.x;
  const int bb = blk >> 4, sl = blk & 15, tid = threadIdx.x;
  const int hd = sl >> 1, hf16 = sl & 1;   // head + half-of-head for this slice
  unsigned* flags = p.flags + bb * 256;

  __shared__ __align__(16) float hsh[D];
  __shared__ __align__(16) float ash[64];
  __shared__ __align__(16) float lg[128];
  __shared__ float qsh[DH], osh[DH], score[TF], red[4];
  __shared__ float wval[2]; __shared__ int widx[2];
  __shared__ float stage[NSLOT * D];
  __shared__ float kls[NLAYER][TF][DH + 1], vls[NLAYER][TF][DH + 1];
  __shared__ float kcls[NLAYER][NSLOT][DH + 1], vcls[NLAYER][NSLOT][DH + 1];

  // ---- tagged-dataflow exchange: 16 partials {tag:32,float:32}, one RT ----
  auto fold16 = [&](const u64* P, unsigned exp) -> float {
    const u64* b0  = P + (bb * 16 +  0) * 256 + tid;
    const u64* b2  = P + (bb * 16 +  2) * 256 + tid;
    const u64* b4  = P + (bb * 16 +  4) * 256 + tid;
    const u64* b6  = P + (bb * 16 +  6) * 256 + tid;
    const u64* b8  = P + (bb * 16 +  8) * 256 + tid;
    const u64* b10 = P + (bb * 16 + 10) * 256 + tid;
    const u64* b12 = P + (bb * 16 + 12) * 256 + tid;
    const u64* b14 = P + (bb * 16 + 14) * 256 + tid;
    u64 v0,v1,v2,v3,v4,v5,v6,v7,v8,v9,v10,v11,v12,v13,v14,v15;
    for (;;) {
      asm volatile(
        "global_load_dwordx2 %0, %16, off sc0 sc1\n\t"
        "global_load_dwordx2 %1, %16, off offset:2048 sc0 sc1\n\t"
        "global_load_dwordx2 %2, %17, off sc0 sc1\n\t"
        "global_load_dwordx2 %3, %17, off offset:2048 sc0 sc1\n\t"
        "global_load_dwordx2 %4, %18, off sc0 sc1\n\t"
        "global_load_dwordx2 %5, %18, off offset:2048 sc0 sc1\n\t"
        "global_load_dwordx2 %6, %19, off sc0 sc1\n\t"
        "global_load_dwordx2 %7, %19, off offset:2048 sc0 sc1\n\t"
        "global_load_dwordx2 %8, %20, off sc0 sc1\n\t"
        "global_load_dwordx2 %9, %20, off offset:2048 sc0 sc1\n\t"
        "global_load_dwordx2 %10, %21, off sc0 sc1\n\t"
        "global_load_dwordx2 %11, %21, off offset:2048 sc0 sc1\n\t"
        "global_load_dwordx2 %12, %22, off sc0 sc1\n\t"
        "global_load_dwordx2 %13, %22, off offset:2048 sc0 sc1\n\t"
        "global_load_dwordx2 %14, %23, off sc0 sc1\n\t"
        "global_load_dwordx2 %15, %23, off offset:2048 sc0 sc1\n\t"
        "s_waitcnt vmcnt(0)"
        : "=&v"(v0), "=&v"(v1), "=&v"(v2), "=&v"(v3),
          "=&v"(v4), "=&v"(v5), "=&v"(v6), "=&v"(v7),
          "=&v"(v8), "=&v"(v9), "=&v"(v10), "=&v"(v11),
          "=&v"(v12), "=&v"(v13), "=&v"(v14), "=&v"(v15)
        : "v"(b0), "v"(b2), "v"(b4), "v"(b6),
          "v"(b8), "v"(b10), "v"(b12), "v"(b14) : "memory");
      const unsigned e = exp;
      bool ok = (unsigned)(v0>>32)==e && (unsigned)(v1>>32)==e &&
                (unsigned)(v2>>32)==e && (unsigned)(v3>>32)==e &&
                (unsigned)(v4>>32)==e && (unsigned)(v5>>32)==e &&
                (unsigned)(v6>>32)==e && (unsigned)(v7>>32)==e &&
                (unsigned)(v8>>32)==e && (unsigned)(v9>>32)==e &&
                (unsigned)(v10>>32)==e && (unsigned)(v11>>32)==e &&
                (unsigned)(v12>>32)==e && (unsigned)(v13>>32)==e &&
                (unsigned)(v14>>32)==e && (unsigned)(v15>>32)==e;
      if (ok) break;
      __builtin_amdgcn_s_sleep(1);
    }
    const float s0=__uint_as_float((unsigned)v0),  s1=__uint_as_float((unsigned)v1);
    const float s2=__uint_as_float((unsigned)v2),  s3=__uint_as_float((unsigned)v3);
    const float s4=__uint_as_float((unsigned)v4),  s5=__uint_as_float((unsigned)v5);
    const float s6=__uint_as_float((unsigned)v6),  s7=__uint_as_float((unsigned)v7);
    const float s8=__uint_as_float((unsigned)v8),  s9=__uint_as_float((unsigned)v9);
    const float s10=__uint_as_float((unsigned)v10),s11=__uint_as_float((unsigned)v11);
    const float s12=__uint_as_float((unsigned)v12),s13=__uint_as_float((unsigned)v13);
    const float s14=__uint_as_float((unsigned)v14),s15=__uint_as_float((unsigned)v15);
    return (((s0+s1)+(s2+s3))+((s4+s5)+(s6+s7)))
         + (((s8+s9)+(s10+s11))+((s12+s13)+(s14+s15)));
  };

  int lastAmax = 0;

  // tri: 16 producers x {smax, ssum, sarg}; lg[128] holds this block's logits
  auto consume_tri = [&](int row, unsigned exp) {
    float smax16[16], ssum16[16]; int sarg16[16];
    for (;;) {
      bool ok = true;
      #pragma unroll
      for (int j = 0; j < 16; ++j) {
        const u64 A = cload64(&p.tri[(bb * 16 + j) * 4 + 0]);
        const u64 B = cload64(&p.tri[(bb * 16 + j) * 4 + 1]);
        const u64 C = cload64(&p.tri[(bb * 16 + j) * 4 + 2]);
        ok = ok && ((unsigned)(A >> 32) == exp) && ((unsigned)(B >> 32) == exp)
                && ((unsigned)(C >> 32) == exp);
        smax16[j] = __uint_as_float((unsigned)A);
        ssum16[j] = __uint_as_float((unsigned)B);
        sarg16[j] = (int)(unsigned)C;
      }
      if (ok) break;
      __builtin_amdgcn_s_sleep(1);
    }
    float gm = smax16[0];
    #pragma unroll
    for (int j = 1; j < 16; ++j) gm = fmaxf(gm, smax16[j]);
    float gs = 0.f; float best = -1e30f; int am = 0;
    #pragma unroll
    for (int j = 0; j < 16; ++j) {
      gs += ssum16[j] * expf(smax16[j] - gm);
      if (smax16[j] > best) { best = smax16[j]; am = j * 128 + sarg16[j]; } // first-index
    }
    const float lse = gm + logf(gs);
    if (tid < 128)
      p.out_lp[(bb * GENLEN + row) * VOCAB + sl * 128 + tid] = lg[tid] - lse;
    if (sl == 0 && tid == 0)
      p.out_z[bb * VOCAB * GENLEN + am * GENLEN + row] = 1.0f;
    lastAmax = am;
  };

  // ---- zero K/V LDS (rows > t read with 0-weights) ----
  for (int i = tid; i < NLAYER * TF * (DH + 1); i += 256) {
    (&kls[0][0][0])[i] = 0.f;
    (&vls[0][0][0])[i] = 0.f;
  }

  // ================= init: enc = slots @ W_slot_proj (cols sl*16..) =================
  if (tid < 16) {
    const int c = sl * 16 + tid;
    float acc[NSLOT] = {0.f,0.f,0.f,0.f,0.f,0.f,0.f};
    #pragma unroll 8
    for (int i = 0; i < D; ++i) {
      const float w = p.W_slot_proj[i * D + c];
      #pragma unroll
      for (int s = 0; s < NSLOT; ++s) acc[s] += p.slots[(bb * NSLOT + s) * D + i] * w;
    }
    for (int s = 0; s < NSLOT; ++s) cstore(&p.enc[(bb * NSLOT + s) * D + c], acc[s]);
  }
  {
    __syncthreads();
    if (tid == 0) __hip_atomic_store(flags + sl, 1u, __ATOMIC_RELAXED, SCOPE_AGENT);
    if (tid == 0) {
      u32x4 f0, f1, f2, f3;
      for (;;) {
        asm volatile(
          "global_load_dwordx4 %0, %4, off sc0 sc1\n\t"
          "global_load_dwordx4 %1, %4, off offset:16 sc0 sc1\n\t"
          "global_load_dwordx4 %2, %4, off offset:32 sc0 sc1\n\t"
          "global_load_dwordx4 %3, %4, off offset:48 sc0 sc1\n\t"
          "s_waitcnt vmcnt(0)"
          : "=&v"(f0), "=&v"(f1), "=&v"(f2), "=&v"(f3) : "v"(flags) : "memory");
        if (f0.x && f0.y && f0.z && f0.w && f1.x && f1.y && f1.z && f1.w &&
            f2.x && f2.y && f2.z && f2.w && f3.x && f3.y && f3.z && f3.w)
          break;
        __builtin_amdgcn_s_sleep(1);
      }
    }
    __syncthreads();
    asm volatile("" ::: "memory");
  }

  // ============ init: cross K/V for this block's head -> LDS (full head) ============
  {
    for (int i = tid; i < NSLOT * D; i += 256) stage[i] = cload(&p.enc[bb * NSLOT * D + i]);
    __syncthreads();
    const int l = tid >> 6, g = tid & 63, c32 = g >> 1, mat = g & 1;
    const float* W = (mat ? p.Wv_c : p.Wk_c) + l * D * D + hd * DH + c32;
    float acc[NSLOT] = {0.f,0.f,0.f,0.f,0.f,0.f,0.f};
    #pragma unroll 8
    for (int i = 0; i < D; ++i) {
      const float w = W[i * D];
      #pragma unroll
      for (int s = 0; s < NSLOT; ++s) acc[s] += stage[s * D + i] * w;
    }
    if (mat) { for (int s = 0; s < NSLOT; ++s) vcls[l][s][c32] = acc[s]; }
    else     { for (int s = 0; s < NSLOT; ++s) kcls[l][s][c32] = acc[s]; }
    __syncthreads();
  }

  u64* Pbuf[2] = {p.P0, p.P1};
  int par = 0;
  unsigned ctr = 0;
  float x = 0.f;   // replicated residual (identical bits in all 16 slice-blocks)

  // ================================ generation loop ================================
  #pragma unroll 1
  for (int t = 0; t < GENLEN; ++t) {
    #pragma unroll 1
    for (int l = 0; l < NLAYER; ++l) {
      // ------------------------------- SELF-ATTN -------------------------------
      {
        const unsigned expect = ctr; ++ctr; const unsigned wtag = ctr;
        const int mm = tid >> 6, g = tid & 63, c32 = g >> 1, half = g & 1;
        const float* Wqkv = (mm == 0 ? p.Wq_s : (mm == 1 ? p.Wk_s : p.Wv_s))
                          + l * D * D + hd * DH + c32;
        float preq[32];
        if (tid < 192) {
          #pragma unroll
          for (int k = 0; k < 32; ++k) preq[k] = Wqkv[(size_t)(half * 128 + k) * D];
        }
        float wo[16];
        {
          const float* W = p.Wo_s + l * D * D + (hd * DH + hf16 * 16) * D + tid;
          #pragma unroll
          for (int k = 0; k < 16; ++k) wo[k] = W[(size_t)k * D];
        }

        if (l == 0) {
          int tok = 0;
          if (t > 0) { consume_tri(t - 1, expect); tok = lastAmax + 1; }
          x = p.dict_emb[tok * D + tid] + p.pe[t * D + tid];
        } else {
          x += fold16(Pbuf[par], expect);
        }
        // post-fold: issue second QKV block; overlaps the LN below
        float preq2[32];
        if (tid < 192) {
          #pragma unroll
          for (int k = 0; k < 32; ++k)
            preq2[k] = Wqkv[(size_t)(half * 128 + 32 + k) * D];
        }
        const float mean = blockSum(x, red) * (1.f / D);
        const float dv = x - mean;
        const float var = blockSum(dv * dv, red) * (1.f / D);
        const float hval = dv * (1.f / sqrtf(var + 1e-5f)) * p.ln_self_w[l * D + tid]
                         + p.ln_self_b[l * D + tid];
        if (l == 0) x = hval;                 // SLATE quirk
        hsh[tid] = hval;
        __syncthreads();

        if (tid < 192) {
          float acc = dotStreamPre2<128>(Wqkv, hsh, half * 128, D, preq, preq2);
          acc += __shfl_xor(acc, 1);
          if (half == 0) {
            if (mm == 0)      qsh[c32] = acc * 0.17677669529663689f;   // dh^-0.5
            else if (mm == 1) kls[l][t][c32] = acc;
            else              vls[l][t][c32] = acc;
          }
        }
        __syncthreads();

        // softmax + PV fused in wave 0 (same-wave LDS ops are ordered; no barrier)
        if (tid < 64) {
          float s = -1e30f;
          if (tid <= t) {
            float a = 0.f;
            #pragma unroll
            for (int r = 0; r < DH; ++r) a += qsh[r] * kls[l][tid][r];
            s = a;
          }
          float m = s;
          #pragma unroll
          for (int o = 32; o > 0; o >>= 1) m = fmaxf(m, __shfl_xor(m, o));
          const float e = (tid <= t) ? expf(s - m) : 0.f;
          float sum = e;
          #pragma unroll
          for (int o = 32; o > 0; o >>= 1) sum += __shfl_xor(sum, o);
          const float inv = 1.f / sum;
          if (tid < TF) score[tid] = e * inv;
          // PV: lanes 0..31 of the same wave read score written above
          if (tid < DH) {
            float a = 0.f;
            #pragma unroll
            for (int pp = 0; pp < TF; ++pp) a = fmaf(score[pp], vls[l][pp][tid], a);
            osh[tid] = a;
          }
        }
        __syncthreads();
        {
          float a0 = 0.f;
          #pragma unroll
          for (int k = 0; k < 16; ++k) a0 = fmaf(osh[hf16 * 16 + k], wo[k], a0);
          cstore64(&Pbuf[par ^ 1][(bb * 16 + sl) * 256 + tid], packt(wtag, a0));
        }
        par ^= 1;
      }

      // ------------------------------- CROSS-ATTN -------------------------------
      {
        const unsigned expect = ctr; ++ctr; const unsigned wtag = ctr;
        const int c32 = tid >> 3, sub = tid & 7;
        float wq[32];
        {
          const float* W = p.Wq_c + l * D * D + hd * DH + c32;
          #pragma unroll
          for (int k = 0; k < 32; ++k) wq[k] = W[(size_t)(sub * 32 + k) * D];
        }
        float woc[16];
        {
          const float* W = p.Wo_c + l * D * D + (hd * DH + hf16 * 16) * D + tid;
          #pragma unroll
          for (int k = 0; k < 16; ++k) woc[k] = W[(size_t)k * D];
        }

        x += fold16(Pbuf[par], expect);
        const float mean = blockSum(x, red) * (1.f / D);
        const float dv = x - mean;
        const float var = blockSum(dv * dv, red) * (1.f / D);
        hsh[tid] = dv * (1.f / sqrtf(var + 1e-5f)) * p.ln_cross_w[l * D + tid]
                 + p.ln_cross_b[l * D + tid];
        __syncthreads();

        {
          float acc = dot32(wq, hsh, sub * 32);
          acc += __shfl_xor(acc, 1);
          acc += __shfl_xor(acc, 2);
          acc += __shfl_xor(acc, 4);
          if (sub == 0) qsh[c32] = acc * 0.17677669529663689f;
        }
        __syncthreads();

        // softmax + PV fused in wave 0
        if (tid < 64) {
          float s = -1e30f;
          if (tid < NSLOT) {
            float a = 0.f;
            #pragma unroll
            for (int r = 0; r < DH; ++r) a += qsh[r] * kcls[l][tid][r];
            s = a;
          }
          float m = s;
          #pragma unroll
          for (int o = 32; o > 0; o >>= 1) m = fmaxf(m, __shfl_xor(m, o));
          const float e = (tid < NSLOT) ? expf(s - m) : 0.f;
          float sum = e;
          #pragma unroll
          for (int o = 32; o > 0; o >>= 1) sum += __shfl_xor(sum, o);
          const float inv = 1.f / sum;
          if (tid < NSLOT) score[tid] = e * inv;
          if (tid < DH) {
            float a = 0.f;
            #pragma unroll
            for (int s2 = 0; s2 < NSLOT; ++s2) a = fmaf(score[s2], vcls[l][s2][tid], a);
            osh[tid] = a;
          }
        }
        __syncthreads();
        {
          float a0 = 0.f;
          #pragma unroll
          for (int k = 0; k < 16; ++k) a0 = fmaf(osh[hf16 * 16 + k], woc[k], a0);
          cstore64(&Pbuf[par ^ 1][(bb * 16 + sl) * 256 + tid], packt(wtag, a0));
        }
        par ^= 1;
      }

      // ---------------------------------- FFN ----------------------------------
      {
        const unsigned expect = ctr; ++ctr; const unsigned wtag = ctr;
        // W1: 64 cols/block, split-K x4, BOTH halves prefetched
        const int c64 = tid >> 2, q4 = tid & 3, c = sl * 64 + c64;
        const float* W1p = p.W1 + l * D * FFDIM + c;
        float w1A[32], w1B[32];
        {
          #pragma unroll
          for (int k = 0; k < 32; ++k) w1A[k] = W1p[(size_t)(q4 * 64 + k) * FFDIM];
          #pragma unroll
          for (int k = 0; k < 32; ++k) w1B[k] = W1p[(size_t)(q4 * 64 + 32 + k) * FFDIM];
        }
        // W2: 64-row slice, first half pre-fold
        const float* W2p = p.W2 + l * FFDIM * D + sl * 64 * D + tid;
        float w2A[32];
        {
          #pragma unroll
          for (int k = 0; k < 32; ++k) w2A[k] = W2p[(size_t)k * D];
        }

        x += fold16(Pbuf[par], expect);
        // post-fold: second W2 half; overlaps LN + W1 compute
        float w2B[32];
        {
          #pragma unroll
          for (int k = 0; k < 32; ++k) w2B[k] = W2p[(size_t)(32 + k) * D];
        }
        const float mean = blockSum(x, red) * (1.f / D);
        const float dv = x - mean;
        const float var = blockSum(dv * dv, red) * (1.f / D);
        hsh[tid] = dv * (1.f / sqrtf(var + 1e-5f)) * p.ln_ffn_w[l * D + tid]
                 + p.ln_ffn_b[l * D + tid];
        __syncthreads();

        {
          float acc = dot64_2(hsh, q4 * 64, w1A, w1B);
          acc += __shfl_xor(acc, 1);
          acc += __shfl_xor(acc, 2);
          if (q4 == 0) ash[c64] = fmaxf(acc + p.b1[l * FFDIM + c], 0.f);
        }
        __syncthreads();
        {
          float acc = dot64_2(ash, 0, w2A, w2B);
          if (sl == 0) acc += p.b2[l * D + tid];
          cstore64(&Pbuf[par ^ 1][(bb * 16 + sl) * 256 + tid], packt(wtag, acc));
        }
        __syncthreads();
      }
      par ^= 1;
    }

    // --------------------------------- LOGITS ---------------------------------
    {
      const unsigned expect = ctr; ++ctr; const unsigned wtag = ctr;
      // 128 cols/block, split-K x2
      const int j = tid >> 1, hf = tid & 1;
      const float* Wop = p.W_out + sl * 128 + j;
      float prewoA[32];
      {
        #pragma unroll
        for (int k = 0; k < 32; ++k) prewoA[k] = Wop[(size_t)(hf * 128 + k) * VOCAB];
      }

      x += fold16(Pbuf[par], expect);
      // post-fold: second block; overlaps LN
      float prewoB[32];
      {
        #pragma unroll
        for (int k = 0; k < 32; ++k)
          prewoB[k] = Wop[(size_t)(hf * 128 + 32 + k) * VOCAB];
      }
      const float mean = blockSum(x, red) * (1.f / D);
      const float dv = x - mean;
      const float var = blockSum(dv * dv, red) * (1.f / D);
      hsh[tid] = dv * (1.f / sqrtf(var + 1e-5f)) * p.ln_f_w[tid] + p.ln_f_b[tid];
      __syncthreads();
      {
        float acc = dotStreamPre2<128>(Wop, hsh, hf * 128, VOCAB, prewoA, prewoB);
        acc += __shfl_xor(acc, 1);
        if (hf == 0) lg[j] = acc;
      }
      __syncthreads();

      // slice-local max/argmax over 128 cols (threads 0..127, waves 0-1)
      float myv = (tid < 128) ? lg[tid] : -1e30f;
      {
        float v = myv; int idx = (tid < 128) ? tid : 0x7fffffff;
        #pragma unroll
        for (int o = 32; o > 0; o >>= 1) {
          const float v2 = __shfl_xor(v, o);
          const int   i2 = __shfl_xor(idx, o);
          if (v2 > v || (v2 == v && i2 < idx)) { v = v2; idx = i2; }
        }
        const int w = tid >> 6;
        if (w < 2 && (tid & 63) == 0) { wval[w] = v; widx[w] = idx; }
      }
      __syncthreads();
      float smax = wval[0]; int sarg = widx[0];
      if (wval[1] > smax || (wval[1] == smax && widx[1] < sarg)) { smax = wval[1]; sarg = widx[1]; }
      const float ssum = blockSum((tid < 128) ? expf(myv - smax) : 0.f, red);
      if (tid == 0) {
        cstore64(&p.tri[(bb * 16 + sl) * 4 + 0], packt(wtag, smax));
        cstore64(&p.tri[(bb * 16 + sl) * 4 + 1], packt(wtag, ssum));
        cstore64(&p.tri[(bb * 16 + sl) * 4 + 2], ((u64)wtag << 32) | (unsigned)sarg);
      }
      __syncthreads();
    }
  }

  // ------------------------------ final step output ------------------------------
  consume_tri(GENLEN - 1, ctr);
}

extern "C" void kernel_launch(void* const* d_in, const int* in_sizes, int n_in,
                              void* d_out, int out_size, void* d_ws, size_t ws_size,
                              hipStream_t stream)
{
  Params p;
  const float* const* in = (const float* const*)d_in;
  p.slots = in[0];  p.W_slot_proj = in[1]; p.dict_emb = in[2]; p.pe = in[3];
  p.ln_self_w = in[4];  p.ln_self_b = in[5];
  p.Wq_s = in[6];  p.Wk_s = in[7];  p.Wv_s = in[8];  p.Wo_s = in[9];
  p.ln_cross_w = in[10]; p.ln_cross_b = in[11];
  p.Wq_c = in[12]; p.Wk_c = in[13]; p.Wv_c = in[14]; p.Wo_c = in[15];
  p.ln_ffn_w = in[16]; p.ln_ffn_b = in[17];
  p.W1 = in[18]; p.b1 = in[19]; p.W2 = in[20]; p.b2 = in[21];
  p.ln_f_w = in[22]; p.ln_f_b = in[23]; p.W_out = in[24];

  // zeroed region: flags (8KB) | P0 (256KB) | P1 (256KB) | tri (4KB)
  p.flags = (unsigned*)d_ws;
  p.P0 = (u64*)((char*)d_ws + 8192);
  p.P1 = p.P0 + BATCH * NSL * 256;
  p.tri = p.P1 + BATCH * NSL * 256;
  const size_t zero_bytes = 8192 + 2 * (size_t)BATCH * NSL * 256 * 8
                          + (size_t)BATCH * NSL * 4 * 8;
  p.enc = (float*)((char*)d_ws + ((zero_bytes + 255) & ~(size_t)255));

  p.out_z  = (float*)d_out;
  p.out_lp = (float*)d_out + BATCH * VOCAB * GENLEN;

  hipMemsetAsync(d_ws, 0, zero_bytes, stream);
  hipMemsetAsync(d_out, 0, (size_t)out_size * sizeof(float), stream);

  mega_kernel<<<BATCH * NSL, 256, 0, stream>>>(p);
}

// Round 18
// 1320.185 us; speedup vs baseline: 1.5096x; 1.5096x over previous
//
#include <hip/hip_runtime.h>

#define D       256
#define DH      32
#define FFDIM   1024
#define VOCAB   2048
#define GENLEN  16
#define BATCH   8
#define NSLOT   7
#define TF      17
#define NLAYER  4
#define NSL     16

#define SCOPE_AGENT __HIP_MEMORY_SCOPE_AGENT

typedef float    f32x4 __attribute__((ext_vector_type(4)));
typedef unsigned u32x4 __attribute__((ext_vector_type(4)));
typedef unsigned long long u64;

struct Params {
  const float *slots, *W_slot_proj, *dict_emb, *pe;
  const float *ln_self_w, *ln_self_b, *Wq_s, *Wk_s, *Wv_s, *Wo_s;
  const float *ln_cross_w, *ln_cross_b, *Wq_c, *Wk_c, *Wv_c, *Wo_c;
  const float *ln_ffn_w, *ln_ffn_b, *W1, *b1, *W2, *b2;
  const float *ln_f_w, *ln_f_b, *W_out;
  float *enc;
  u64 *P0, *P1, *tri;
  unsigned *flags;
  float *out_z, *out_lp;
};

__device__ __forceinline__ float cload(const float* p) {
  return __hip_atomic_load(p, __ATOMIC_RELAXED, SCOPE_AGENT);
}
__device__ __forceinline__ void cstore(float* p, float v) {
  __hip_atomic_store(p, v, __ATOMIC_RELAXED, SCOPE_AGENT);
}
__device__ __forceinline__ u64 cload64(const u64* p) {
  return __hip_atomic_load(p, __ATOMIC_RELAXED, SCOPE_AGENT);
}
__device__ __forceinline__ void cstore64(u64* p, u64 v) {
  __hip_atomic_store(p, v, __ATOMIC_RELAXED, SCOPE_AGENT);
}
__device__ __forceinline__ u64 packt(unsigned tag, float v) {
  return ((u64)tag << 32) | (u64)__float_as_uint(v);
}

__device__ __forceinline__ float blockSum(float v, float* red) {
  #pragma unroll
  for (int o = 32; o > 0; o >>= 1) v += __shfl_down(v, o);
  const int lane = threadIdx.x & 63, w = threadIdx.x >> 6;
  if (lane == 0) red[w] = v;
  __syncthreads();
  float s = red[0] + red[1] + red[2] + red[3];
  __syncthreads();
  return s;
}

// ---- double-buffered streaming GEMV (live set = 64 regs; spill rule) ----
template<int N>
__device__ __forceinline__ float dotStreamPre(const float* __restrict__ W,
                                              const float* __restrict__ h,
                                              int i0, int ld,
                                              const float* __restrict__ pre) {
  float pA[32], pB[32];
  #pragma unroll
  for (int k = 0; k < 32; ++k) pA[k] = pre[k];
  #pragma unroll
  for (int k = 0; k < 32; ++k) pB[k] = W[(size_t)(i0 + 32 + k) * ld];
  float acc = 0.f;
  #pragma unroll 1
  for (int u = 0; u < N; u += 64) {
    const f32x4* h4 = reinterpret_cast<const f32x4*>(h + i0 + u);
    #pragma unroll
    for (int k = 0; k < 8; ++k) {
      const f32x4 hv = h4[k];
      acc = fmaf(hv.x, pA[4*k+0], acc); acc = fmaf(hv.y, pA[4*k+1], acc);
      acc = fmaf(hv.z, pA[4*k+2], acc); acc = fmaf(hv.w, pA[4*k+3], acc);
    }
    if (u + 64 < N) {
      #pragma unroll
      for (int k = 0; k < 32; ++k) pA[k] = W[(size_t)(i0 + u + 64 + k) * ld];
    }
    #pragma unroll
    for (int k = 0; k < 8; ++k) {
      const f32x4 hv = h4[8 + k];
      acc = fmaf(hv.x, pB[4*k+0], acc); acc = fmaf(hv.y, pB[4*k+1], acc);
      acc = fmaf(hv.z, pB[4*k+2], acc); acc = fmaf(hv.w, pB[4*k+3], acc);
    }
    if (u + 96 < N) {
      #pragma unroll
      for (int k = 0; k < 32; ++k) pB[k] = W[(size_t)(i0 + u + 96 + k) * ld];
    }
  }
  return acc;
}

// 64-row dot with BOTH halves preloaded (zero runtime weight loads)
__device__ __forceinline__ float dot64_2(const float* __restrict__ h, int i0,
                                         const float* __restrict__ A,
                                         const float* __restrict__ B) {
  float acc = 0.f;
  const f32x4* h4 = reinterpret_cast<const f32x4*>(h + i0);
  #pragma unroll
  for (int k = 0; k < 8; ++k) {
    const f32x4 hv = h4[k];
    acc = fmaf(hv.x, A[4*k+0], acc); acc = fmaf(hv.y, A[4*k+1], acc);
    acc = fmaf(hv.z, A[4*k+2], acc); acc = fmaf(hv.w, A[4*k+3], acc);
  }
  #pragma unroll
  for (int k = 0; k < 8; ++k) {
    const f32x4 hv = h4[8 + k];
    acc = fmaf(hv.x, B[4*k+0], acc); acc = fmaf(hv.y, B[4*k+1], acc);
    acc = fmaf(hv.z, B[4*k+2], acc); acc = fmaf(hv.w, B[4*k+3], acc);
  }
  return acc;
}

__device__ __forceinline__ float dot32(const float* __restrict__ w,
                                       const float* __restrict__ h, int i0) {
  float acc = 0.f;
  const f32x4* h4 = reinterpret_cast<const f32x4*>(h + i0);
  #pragma unroll
  for (int k = 0; k < 8; ++k) {
    const f32x4 hv = h4[k];
    acc = fmaf(hv.x, w[4*k+0], acc); acc = fmaf(hv.y, w[4*k+1], acc);
    acc = fmaf(hv.z, w[4*k+2], acc); acc = fmaf(hv.w, w[4*k+3], acc);
  }
  return acc;
}

__global__ __launch_bounds__(256, 1) void mega_kernel(Params p)
{
  const int blk = blockIdx.x;
  const int bb = blk >> 4, sl = blk & 15, tid = threadIdx.x;
  const int hd = sl >> 1, hf16 = sl & 1;   // head + half-of-head for this slice
  unsigned* flags = p.flags + bb * 256;

  __shared__ __align__(16) float hsh[D];
  __shared__ __align__(16) float ash[64];
  __shared__ __align__(16) float lg[128];
  __shared__ float qsh[DH], osh[DH], score[TF], red[4];
  __shared__ float wval[2]; __shared__ int widx[2];
  __shared__ float stage[NSLOT * D];
  __shared__ float kls[NLAYER][TF][DH + 1], vls[NLAYER][TF][DH + 1];
  __shared__ float kcls[NLAYER][NSLOT][DH + 1], vcls[NLAYER][NSLOT][DH + 1];

  // ---- tagged-dataflow exchange: 16 partials {tag:32,float:32}, one RT ----
  auto fold16 = [&](const u64* P, unsigned exp) -> float {
    const u64* b0  = P + (bb * 16 +  0) * 256 + tid;
    const u64* b2  = P + (bb * 16 +  2) * 256 + tid;
    const u64* b4  = P + (bb * 16 +  4) * 256 + tid;
    const u64* b6  = P + (bb * 16 +  6) * 256 + tid;
    const u64* b8  = P + (bb * 16 +  8) * 256 + tid;
    const u64* b10 = P + (bb * 16 + 10) * 256 + tid;
    const u64* b12 = P + (bb * 16 + 12) * 256 + tid;
    const u64* b14 = P + (bb * 16 + 14) * 256 + tid;
    u64 v0,v1,v2,v3,v4,v5,v6,v7,v8,v9,v10,v11,v12,v13,v14,v15;
    for (;;) {
      asm volatile(
        "global_load_dwordx2 %0, %16, off sc0 sc1\n\t"
        "global_load_dwordx2 %1, %16, off offset:2048 sc0 sc1\n\t"
        "global_load_dwordx2 %2, %17, off sc0 sc1\n\t"
        "global_load_dwordx2 %3, %17, off offset:2048 sc0 sc1\n\t"
        "global_load_dwordx2 %4, %18, off sc0 sc1\n\t"
        "global_load_dwordx2 %5, %18, off offset:2048 sc0 sc1\n\t"
        "global_load_dwordx2 %6, %19, off sc0 sc1\n\t"
        "global_load_dwordx2 %7, %19, off offset:2048 sc0 sc1\n\t"
        "global_load_dwordx2 %8, %20, off sc0 sc1\n\t"
        "global_load_dwordx2 %9, %20, off offset:2048 sc0 sc1\n\t"
        "global_load_dwordx2 %10, %21, off sc0 sc1\n\t"
        "global_load_dwordx2 %11, %21, off offset:2048 sc0 sc1\n\t"
        "global_load_dwordx2 %12, %22, off sc0 sc1\n\t"
        "global_load_dwordx2 %13, %22, off offset:2048 sc0 sc1\n\t"
        "global_load_dwordx2 %14, %23, off sc0 sc1\n\t"
        "global_load_dwordx2 %15, %23, off offset:2048 sc0 sc1\n\t"
        "s_waitcnt vmcnt(0)"
        : "=&v"(v0), "=&v"(v1), "=&v"(v2), "=&v"(v3),
          "=&v"(v4), "=&v"(v5), "=&v"(v6), "=&v"(v7),
          "=&v"(v8), "=&v"(v9), "=&v"(v10), "=&v"(v11),
          "=&v"(v12), "=&v"(v13), "=&v"(v14), "=&v"(v15)
        : "v"(b0), "v"(b2), "v"(b4), "v"(b6),
          "v"(b8), "v"(b10), "v"(b12), "v"(b14) : "memory");
      const unsigned e = exp;
      bool ok = (unsigned)(v0>>32)==e && (unsigned)(v1>>32)==e &&
                (unsigned)(v2>>32)==e && (unsigned)(v3>>32)==e &&
                (unsigned)(v4>>32)==e && (unsigned)(v5>>32)==e &&
                (unsigned)(v6>>32)==e && (unsigned)(v7>>32)==e &&
                (unsigned)(v8>>32)==e && (unsigned)(v9>>32)==e &&
                (unsigned)(v10>>32)==e && (unsigned)(v11>>32)==e &&
                (unsigned)(v12>>32)==e && (unsigned)(v13>>32)==e &&
                (unsigned)(v14>>32)==e && (unsigned)(v15>>32)==e;
      if (ok) break;
      __builtin_amdgcn_s_sleep(1);
    }
    const float s0=__uint_as_float((unsigned)v0),  s1=__uint_as_float((unsigned)v1);
    const float s2=__uint_as_float((unsigned)v2),  s3=__uint_as_float((unsigned)v3);
    const float s4=__uint_as_float((unsigned)v4),  s5=__uint_as_float((unsigned)v5);
    const float s6=__uint_as_float((unsigned)v6),  s7=__uint_as_float((unsigned)v7);
    const float s8=__uint_as_float((unsigned)v8),  s9=__uint_as_float((unsigned)v9);
    const float s10=__uint_as_float((unsigned)v10),s11=__uint_as_float((unsigned)v11);
    const float s12=__uint_as_float((unsigned)v12),s13=__uint_as_float((unsigned)v13);
    const float s14=__uint_as_float((unsigned)v14),s15=__uint_as_float((unsigned)v15);
    return (((s0+s1)+(s2+s3))+((s4+s5)+(s6+s7)))
         + (((s8+s9)+(s10+s11))+((s12+s13)+(s14+s15)));
  };

  int lastAmax = 0;

  // tri: 16 producers x {smax, ssum, sarg}; lg[128] holds this block's logits
  auto consume_tri = [&](int row, unsigned exp) {
    float smax16[16], ssum16[16]; int sarg16[16];
    for (;;) {
      bool ok = true;
      #pragma unroll
      for (int j = 0; j < 16; ++j) {
        const u64 A = cload64(&p.tri[(bb * 16 + j) * 4 + 0]);
        const u64 B = cload64(&p.tri[(bb * 16 + j) * 4 + 1]);
        const u64 C = cload64(&p.tri[(bb * 16 + j) * 4 + 2]);
        ok = ok && ((unsigned)(A >> 32) == exp) && ((unsigned)(B >> 32) == exp)
                && ((unsigned)(C >> 32) == exp);
        smax16[j] = __uint_as_float((unsigned)A);
        ssum16[j] = __uint_as_float((unsigned)B);
        sarg16[j] = (int)(unsigned)C;
      }
      if (ok) break;
      __builtin_amdgcn_s_sleep(1);
    }
    float gm = smax16[0];
    #pragma unroll
    for (int j = 1; j < 16; ++j) gm = fmaxf(gm, smax16[j]);
    float gs = 0.f; float best = -1e30f; int am = 0;
    #pragma unroll
    for (int j = 0; j < 16; ++j) {
      gs += ssum16[j] * expf(smax16[j] - gm);
      if (smax16[j] > best) { best = smax16[j]; am = j * 128 + sarg16[j]; } // first-index
    }
    const float lse = gm + logf(gs);
    if (tid < 128)
      p.out_lp[(bb * GENLEN + row) * VOCAB + sl * 128 + tid] = lg[tid] - lse;
    if (sl == 0 && tid == 0)
      p.out_z[bb * VOCAB * GENLEN + am * GENLEN + row] = 1.0f;
    lastAmax = am;
  };

  // ---- zero K/V LDS (rows > t read with 0-weights) ----
  for (int i = tid; i < NLAYER * TF * (DH + 1); i += 256) {
    (&kls[0][0][0])[i] = 0.f;
    (&vls[0][0][0])[i] = 0.f;
  }

  // ================= init: enc = slots @ W_slot_proj (cols sl*16..) =================
  if (tid < 16) {
    const int c = sl * 16 + tid;
    float acc[NSLOT] = {0.f,0.f,0.f,0.f,0.f,0.f,0.f};
    #pragma unroll 8
    for (int i = 0; i < D; ++i) {
      const float w = p.W_slot_proj[i * D + c];
      #pragma unroll
      for (int s = 0; s < NSLOT; ++s) acc[s] += p.slots[(bb * NSLOT + s) * D + i] * w;
    }
    for (int s = 0; s < NSLOT; ++s) cstore(&p.enc[(bb * NSLOT + s) * D + c], acc[s]);
  }
  {
    __syncthreads();
    if (tid == 0) __hip_atomic_store(flags + sl, 1u, __ATOMIC_RELAXED, SCOPE_AGENT);
    if (tid == 0) {
      u32x4 f0, f1, f2, f3;
      for (;;) {
        asm volatile(
          "global_load_dwordx4 %0, %4, off sc0 sc1\n\t"
          "global_load_dwordx4 %1, %4, off offset:16 sc0 sc1\n\t"
          "global_load_dwordx4 %2, %4, off offset:32 sc0 sc1\n\t"
          "global_load_dwordx4 %3, %4, off offset:48 sc0 sc1\n\t"
          "s_waitcnt vmcnt(0)"
          : "=&v"(f0), "=&v"(f1), "=&v"(f2), "=&v"(f3) : "v"(flags) : "memory");
        if (f0.x && f0.y && f0.z && f0.w && f1.x && f1.y && f1.z && f1.w &&
            f2.x && f2.y && f2.z && f2.w && f3.x && f3.y && f3.z && f3.w)
          break;
        __builtin_amdgcn_s_sleep(1);
      }
    }
    __syncthreads();
    asm volatile("" ::: "memory");
  }

  // ============ init: cross K/V for this block's head -> LDS (full head) ============
  {
    for (int i = tid; i < NSLOT * D; i += 256) stage[i] = cload(&p.enc[bb * NSLOT * D + i]);
    __syncthreads();
    const int l = tid >> 6, g = tid & 63, c32 = g >> 1, mat = g & 1;
    const float* W = (mat ? p.Wv_c : p.Wk_c) + l * D * D + hd * DH + c32;
    float acc[NSLOT] = {0.f,0.f,0.f,0.f,0.f,0.f,0.f};
    #pragma unroll 8
    for (int i = 0; i < D; ++i) {
      const float w = W[i * D];
      #pragma unroll
      for (int s = 0; s < NSLOT; ++s) acc[s] += stage[s * D + i] * w;
    }
    if (mat) { for (int s = 0; s < NSLOT; ++s) vcls[l][s][c32] = acc[s]; }
    else     { for (int s = 0; s < NSLOT; ++s) kcls[l][s][c32] = acc[s]; }
    __syncthreads();
  }

  u64* Pbuf[2] = {p.P0, p.P1};
  int par = 0;
  unsigned ctr = 0;
  float x = 0.f;   // replicated residual (identical bits in all 16 slice-blocks)

  // ================================ generation loop ================================
  #pragma unroll 1
  for (int t = 0; t < GENLEN; ++t) {
    #pragma unroll 1
    for (int l = 0; l < NLAYER; ++l) {
      // ------------------------------- SELF-ATTN -------------------------------
      {
        const unsigned expect = ctr; ++ctr; const unsigned wtag = ctr;
        // QKV for FULL head hd (pair-redundant): 192 threads, split-K x2
        const int mm = tid >> 6, g = tid & 63, c32 = g >> 1, half = g & 1;
        const float* Wqkv = (mm == 0 ? p.Wq_s : (mm == 1 ? p.Wk_s : p.Wv_s))
                          + l * D * D + hd * DH + c32;
        float preq[32];
        if (tid < 192) {
          #pragma unroll
          for (int k = 0; k < 32; ++k) preq[k] = Wqkv[(size_t)(half * 128 + k) * D];
        }
        // Wo row-slice: 16 rows (hd*32 + hf16*16 ..)
        float wo[16];
        {
          const float* W = p.Wo_s + l * D * D + (hd * DH + hf16 * 16) * D + tid;
          #pragma unroll
          for (int k = 0; k < 16; ++k) wo[k] = W[(size_t)k * D];
        }

        if (l == 0) {
          int tok = 0;
          if (t > 0) { consume_tri(t - 1, expect); tok = lastAmax + 1; }
          x = p.dict_emb[tok * D + tid] + p.pe[t * D + tid];
        } else {
          x += fold16(Pbuf[par], expect);
        }
        const float mean = blockSum(x, red) * (1.f / D);
        const float dv = x - mean;
        const float var = blockSum(dv * dv, red) * (1.f / D);
        const float hval = dv * (1.f / sqrtf(var + 1e-5f)) * p.ln_self_w[l * D + tid]
                         + p.ln_self_b[l * D + tid];
        if (l == 0) x = hval;                 // SLATE quirk
        hsh[tid] = hval;
        __syncthreads();

        if (tid < 192) {
          float acc = dotStreamPre<128>(Wqkv, hsh, half * 128, D, preq);
          acc += __shfl_xor(acc, 1);
          if (half == 0) {
            if (mm == 0)      qsh[c32] = acc * 0.17677669529663689f;   // dh^-0.5
            else if (mm == 1) kls[l][t][c32] = acc;
            else              vls[l][t][c32] = acc;
          }
        }
        __syncthreads();

        // softmax + PV fused in wave 0 (same-wave LDS ops are ordered; no barrier
        // between score write and PV read — correctness-proven in R17)
        if (tid < 64) {
          float s = -1e30f;
          if (tid <= t) {
            float a = 0.f;
            #pragma unroll
            for (int r = 0; r < DH; ++r) a += qsh[r] * kls[l][tid][r];
            s = a;
          }
          float m = s;
          #pragma unroll
          for (int o = 32; o > 0; o >>= 1) m = fmaxf(m, __shfl_xor(m, o));
          const float e = (tid <= t) ? expf(s - m) : 0.f;
          float sum = e;
          #pragma unroll
          for (int o = 32; o > 0; o >>= 1) sum += __shfl_xor(sum, o);
          const float inv = 1.f / sum;
          if (tid < TF) score[tid] = e * inv;
          if (tid < DH) {
            float a = 0.f;
            #pragma unroll
            for (int pp = 0; pp < TF; ++pp) a = fmaf(score[pp], vls[l][pp][tid], a);
            osh[tid] = a;
          }
        }
        __syncthreads();
        {
          float a0 = 0.f;
          #pragma unroll
          for (int k = 0; k < 16; ++k) a0 = fmaf(osh[hf16 * 16 + k], wo[k], a0);
          cstore64(&Pbuf[par ^ 1][(bb * 16 + sl) * 256 + tid], packt(wtag, a0));
        }
        par ^= 1;
      }

      // ------------------------------- CROSS-ATTN -------------------------------
      {
        const unsigned expect = ctr; ++ctr; const unsigned wtag = ctr;
        const int c32 = tid >> 3, sub = tid & 7;
        float wq[32];
        {
          const float* W = p.Wq_c + l * D * D + hd * DH + c32;
          #pragma unroll
          for (int k = 0; k < 32; ++k) wq[k] = W[(size_t)(sub * 32 + k) * D];
        }
        float woc[16];
        {
          const float* W = p.Wo_c + l * D * D + (hd * DH + hf16 * 16) * D + tid;
          #pragma unroll
          for (int k = 0; k < 16; ++k) woc[k] = W[(size_t)k * D];
        }

        x += fold16(Pbuf[par], expect);
        const float mean = blockSum(x, red) * (1.f / D);
        const float dv = x - mean;
        const float var = blockSum(dv * dv, red) * (1.f / D);
        hsh[tid] = dv * (1.f / sqrtf(var + 1e-5f)) * p.ln_cross_w[l * D + tid]
                 + p.ln_cross_b[l * D + tid];
        __syncthreads();

        {
          float acc = dot32(wq, hsh, sub * 32);
          acc += __shfl_xor(acc, 1);
          acc += __shfl_xor(acc, 2);
          acc += __shfl_xor(acc, 4);
          if (sub == 0) qsh[c32] = acc * 0.17677669529663689f;
        }
        __syncthreads();

        // softmax + PV fused in wave 0
        if (tid < 64) {
          float s = -1e30f;
          if (tid < NSLOT) {
            float a = 0.f;
            #pragma unroll
            for (int r = 0; r < DH; ++r) a += qsh[r] * kcls[l][tid][r];
            s = a;
          }
          float m = s;
          #pragma unroll
          for (int o = 32; o > 0; o >>= 1) m = fmaxf(m, __shfl_xor(m, o));
          const float e = (tid < NSLOT) ? expf(s - m) : 0.f;
          float sum = e;
          #pragma unroll
          for (int o = 32; o > 0; o >>= 1) sum += __shfl_xor(sum, o);
          const float inv = 1.f / sum;
          if (tid < NSLOT) score[tid] = e * inv;
          if (tid < DH) {
            float a = 0.f;
            #pragma unroll
            for (int s2 = 0; s2 < NSLOT; ++s2) a = fmaf(score[s2], vcls[l][s2][tid], a);
            osh[tid] = a;
          }
        }
        __syncthreads();
        {
          float a0 = 0.f;
          #pragma unroll
          for (int k = 0; k < 16; ++k) a0 = fmaf(osh[hf16 * 16 + k], woc[k], a0);
          cstore64(&Pbuf[par ^ 1][(bb * 16 + sl) * 256 + tid], packt(wtag, a0));
        }
        par ^= 1;
      }

      // ---------------------------------- FFN ----------------------------------
      {
        const unsigned expect = ctr; ++ctr; const unsigned wtag = ctr;
        // W1: 64 cols/block, split-K x4, BOTH halves prefetched (no runtime loads)
        const int c64 = tid >> 2, q4 = tid & 3, c = sl * 64 + c64;
        const float* W1p = p.W1 + l * D * FFDIM + c;
        float w1A[32], w1B[32];
        {
          #pragma unroll
          for (int k = 0; k < 32; ++k) w1A[k] = W1p[(size_t)(q4 * 64 + k) * FFDIM];
          #pragma unroll
          for (int k = 0; k < 32; ++k) w1B[k] = W1p[(size_t)(q4 * 64 + 32 + k) * FFDIM];
        }
        // W2: 64-row slice, pre half
        const float* W2p = p.W2 + l * FFDIM * D + sl * 64 * D + tid;
        float prew2[32];
        {
          #pragma unroll
          for (int k = 0; k < 32; ++k) prew2[k] = W2p[(size_t)k * D];
        }

        x += fold16(Pbuf[par], expect);
        const float mean = blockSum(x, red) * (1.f / D);
        const float dv = x - mean;
        const float var = blockSum(dv * dv, red) * (1.f / D);
        hsh[tid] = dv * (1.f / sqrtf(var + 1e-5f)) * p.ln_ffn_w[l * D + tid]
                 + p.ln_ffn_b[l * D + tid];
        __syncthreads();

        {
          float acc = dot64_2(hsh, q4 * 64, w1A, w1B);
          acc += __shfl_xor(acc, 1);
          acc += __shfl_xor(acc, 2);
          if (q4 == 0) ash[c64] = fmaxf(acc + p.b1[l * FFDIM + c], 0.f);
        }
        __syncthreads();
        {
          float acc = dotStreamPre<64>(W2p, ash, 0, D, prew2);
          if (sl == 0) acc += p.b2[l * D + tid];
          cstore64(&Pbuf[par ^ 1][(bb * 16 + sl) * 256 + tid], packt(wtag, acc));
        }
        __syncthreads();
      }
      par ^= 1;
    }

    // --------------------------------- LOGITS ---------------------------------
    {
      const unsigned expect = ctr; ++ctr; const unsigned wtag = ctr;
      // 128 cols/block, split-K x2
      const int j = tid >> 1, hf = tid & 1;
      const float* Wop = p.W_out + sl * 128 + j;
      float prewo[32];
      {
        #pragma unroll
        for (int k = 0; k < 32; ++k) prewo[k] = Wop[(size_t)(hf * 128 + k) * VOCAB];
      }

      x += fold16(Pbuf[par], expect);
      const float mean = blockSum(x, red) * (1.f / D);
      const float dv = x - mean;
      const float var = blockSum(dv * dv, red) * (1.f / D);
      hsh[tid] = dv * (1.f / sqrtf(var + 1e-5f)) * p.ln_f_w[tid] + p.ln_f_b[tid];
      __syncthreads();
      {
        float acc = dotStreamPre<128>(Wop, hsh, hf * 128, VOCAB, prewo);
        acc += __shfl_xor(acc, 1);
        if (hf == 0) lg[j] = acc;
      }
      __syncthreads();

      // slice-local max/argmax over 128 cols (threads 0..127, waves 0-1)
      float myv = (tid < 128) ? lg[tid] : -1e30f;
      {
        float v = myv; int idx = (tid < 128) ? tid : 0x7fffffff;
        #pragma unroll
        for (int o = 32; o > 0; o >>= 1) {
          const float v2 = __shfl_xor(v, o);
          const int   i2 = __shfl_xor(idx, o);
          if (v2 > v || (v2 == v && i2 < idx)) { v = v2; idx = i2; }
        }
        const int w = tid >> 6;
        if (w < 2 && (tid & 63) == 0) { wval[w] = v; widx[w] = idx; }
      }
      __syncthreads();
      float smax = wval[0]; int sarg = widx[0];
      if (wval[1] > smax || (wval[1] == smax && widx[1] < sarg)) { smax = wval[1]; sarg = widx[1]; }
      const float ssum = blockSum((tid < 128) ? expf(myv - smax) : 0.f, red);
      if (tid == 0) {
        cstore64(&p.tri[(bb * 16 + sl) * 4 + 0], packt(wtag, smax));
        cstore64(&p.tri[(bb * 16 + sl) * 4 + 1], packt(wtag, ssum));
        cstore64(&p.tri[(bb * 16 + sl) * 4 + 2], ((u64)wtag << 32) | (unsigned)sarg);
      }
      __syncthreads();
    }
  }

  // ------------------------------ final step output ------------------------------
  consume_tri(GENLEN - 1, ctr);
}

extern "C" void kernel_launch(void* const* d_in, const int* in_sizes, int n_in,
                              void* d_out, int out_size, void* d_ws, size_t ws_size,
                              hipStream_t stream)
{
  Params p;
  const float* const* in = (const float* const*)d_in;
  p.slots = in[0];  p.W_slot_proj = in[1]; p.dict_emb = in[2]; p.pe = in[3];
  p.ln_self_w = in[4];  p.ln_self_b = in[5];
  p.Wq_s = in[6];  p.Wk_s = in[7];  p.Wv_s = in[8];  p.Wo_s = in[9];
  p.ln_cross_w = in[10]; p.ln_cross_b = in[11];
  p.Wq_c = in[12]; p.Wk_c = in[13]; p.Wv_c = in[14]; p.Wo_c = in[15];
  p.ln_ffn_w = in[16]; p.ln_ffn_b = in[17];
  p.W1 = in[18]; p.b1 = in[19]; p.W2 = in[20]; p.b2 = in[21];
  p.ln_f_w = in[22]; p.ln_f_b = in[23]; p.W_out = in[24];

  // zeroed region: flags (8KB) | P0 (256KB) | P1 (256KB) | tri (4KB)
  p.flags = (unsigned*)d_ws;
  p.P0 = (u64*)((char*)d_ws + 8192);
  p.P1 = p.P0 + BATCH * NSL * 256;
  p.tri = p.P1 + BATCH * NSL * 256;
  const size_t zero_bytes = 8192 + 2 * (size_t)BATCH * NSL * 256 * 8
                          + (size_t)BATCH * NSL * 4 * 8;
  p.enc = (float*)((char*)d_ws + ((zero_bytes + 255) & ~(size_t)255));

  p.out_z  = (float*)d_out;
  p.out_lp = (float*)d_out + BATCH * VOCAB * GENLEN;

  hipMemsetAsync(d_ws, 0, zero_bytes, stream);
  hipMemsetAsync(d_out, 0, (size_t)out_size * sizeof(float), stream);

  mega_kernel<<<BATCH * NSL, 256, 0, stream>>>(p);
}